// Round 3
// baseline (56.977 us; speedup 1.0000x reference)
//
#include <hip/hip_runtime.h>

// out[j] = sum(x) for all j.
// Stage 1: per-block partial sums (float4 vectorized, grid-stride) -> ws.
// Stage 2 (fused): each block re-reduces the 2048 partials (L2-resident),
//                  then broadcast-fills its slice of out with nontemporal
//                  16B stores.

#define NBLK 2048
#define NTHR 256

typedef float vfloat4 __attribute__((ext_vector_type(4)));

__global__ __launch_bounds__(NTHR) void reduce_partial_kernel(
    const vfloat4* __restrict__ x4, const float* __restrict__ x,
    float* __restrict__ partials, int n4, int n)
{
    int tid    = blockIdx.x * blockDim.x + threadIdx.x;
    int stride = gridDim.x * blockDim.x;

    float s = 0.0f;
    for (int i = tid; i < n4; i += stride) {
        vfloat4 v = x4[i];
        s += (v.x + v.y) + (v.z + v.w);
    }
    // scalar tail (n not divisible by 4)
    int tail_start = n4 * 4;
    int tail_n = n - tail_start;
    if (tid < tail_n) s += x[tail_start + tid];

    #pragma unroll
    for (int off = 32; off > 0; off >>= 1)
        s += __shfl_down(s, off, 64);

    __shared__ float smem[NTHR / 64];
    int lane = threadIdx.x & 63;
    int wid  = threadIdx.x >> 6;
    if (lane == 0) smem[wid] = s;
    __syncthreads();
    if (threadIdx.x == 0) {
        float t = 0.0f;
        #pragma unroll
        for (int w = 0; w < NTHR / 64; ++w) t += smem[w];
        partials[blockIdx.x] = t;
    }
}

__global__ __launch_bounds__(NTHR) void fill_total_kernel(
    vfloat4* __restrict__ out4, float* __restrict__ out,
    const float* __restrict__ partials, int n4, int n)
{
    // Per-block re-reduction of the NBLK partials (deterministic tree,
    // identical in every block). 8 KB of reads, L2-resident.
    float s = 0.0f;
    for (int i = threadIdx.x; i < NBLK; i += NTHR) s += partials[i];

    #pragma unroll
    for (int off = 32; off > 0; off >>= 1)
        s += __shfl_down(s, off, 64);

    __shared__ float smem[NTHR / 64];
    __shared__ float total_sh;
    int lane = threadIdx.x & 63;
    int wid  = threadIdx.x >> 6;
    if (lane == 0) smem[wid] = s;
    __syncthreads();
    if (threadIdx.x == 0) {
        float t = 0.0f;
        #pragma unroll
        for (int w = 0; w < NTHR / 64; ++w) t += smem[w];
        total_sh = t;
    }
    __syncthreads();

    float t = total_sh;
    vfloat4 v = { t, t, t, t };

    int tid    = blockIdx.x * blockDim.x + threadIdx.x;
    int stride = gridDim.x * blockDim.x;
    for (int i = tid; i < n4; i += stride)
        __builtin_nontemporal_store(v, &out4[i]);

    int tail_start = n4 * 4;
    int tail_n = n - tail_start;
    if (tid < tail_n) out[tail_start + tid] = t;
}

extern "C" void kernel_launch(void* const* d_in, const int* in_sizes, int n_in,
                              void* d_out, int out_size, void* d_ws, size_t ws_size,
                              hipStream_t stream)
{
    const float*   x    = (const float*)d_in[0];
    const vfloat4* x4   = (const vfloat4*)d_in[0];
    float*         out  = (float*)d_out;
    vfloat4*       out4 = (vfloat4*)d_out;

    int n  = in_sizes[0];
    int n4 = n / 4;

    float* partials = (float*)d_ws;  // NBLK floats

    reduce_partial_kernel<<<NBLK, NTHR, 0, stream>>>(x4, x, partials, n4, n);
    fill_total_kernel<<<NBLK, NTHR, 0, stream>>>(out4, out, partials, n4, out_size);
}